// Round 4
// baseline (90.643 us; speedup 1.0000x reference)
//
#include <hip/hip_runtime.h>
#include <math.h>

// Problem constants (match reference)
#define NI 8    // invariants
#define IL 4    // vars per invariant
#define BL 25   // objects per example
#define P1 64   // unary predicates
#define P2 16   // binary predicates
#define NB 64   // batch

// LDS row strides chosen for bank-conflict avoidance / alignment:
//  cuf: [25][65]  (stride 65 -> distinct-o lanes hit distinct banks)
//  cbf: [25][392] (24*16=384 payload + 8 pad; 392%32=8 -> <=2-way on b128; 1568B rows keep 16B align)
#define CUF_STRIDE 65
#define CBF_STRIDE 392

#define SENTINEL 0xAAAAAAAAu

// Tiny init: set the 512 publish slots to SENTINEL so the leader-spin never
// observes stale garbage, independent of harness poison semantics.
__global__ __launch_bounds__(512) void init_ws_kernel(unsigned int* __restrict__ vals_ws) {
    vals_ws[threadIdx.x] = SENTINEL;
}

__global__ __launch_bounds__(320) void unify_fused_kernel(
    const float* __restrict__ inv_unary_feats,   // (8,4,64)
    const float* __restrict__ inv_binary_feats,  // (8,4,3,16)
    const float* __restrict__ unary_feats,       // (64,25,64)
    const float* __restrict__ binary_feats,      // (64,25,24,16)
    const float* __restrict__ inv_unaryp,        // (8,4,64)
    const float* __restrict__ inv_binaryp,       // (8,4,3,16)
    float* __restrict__ out,                     // uni_sets (64,8,4,25) then inv_select (64,8)
    unsigned int* __restrict__ vals_ws)          // (64*8) published inv_uni bits (init SENTINEL)
{
    __shared__ float cuf_s[BL * CUF_STRIDE];   // 1 - unary_feats[b]
    __shared__ float cbf_s[BL * CBF_STRIDE];   // 1 - binary_feats[b], padded rows
    __shared__ float uc_s[IL * 65];            // sigmoid(unaryp)*unary_feats for this i
    __shared__ float bc_s[IL * 3 * P2];        // sigmoid(binaryp)*binary_feats for this i
    __shared__ float t1_s[IL * BL];
    __shared__ float P_s[BL * 12];             // prod_op(1 - tg*t2) per (o, v*3+vp)
    __shared__ float uni_s[IL * BL];
    __shared__ float ps_s[IL];

    const int bid = blockIdx.x;
    const int b = bid >> 3;   // batch index
    const int i = bid & 7;    // invariant index
    const int t = threadIdx.x;

    // ---- Phase 0: staging ----
    if (t < IL * P1) {
        int v = t >> 6, p = t & 63;
        float pr = inv_unaryp[i * IL * P1 + t];
        float s = 1.0f / (1.0f + expf(-pr));
        uc_s[v * 65 + p] = s * inv_unary_feats[i * IL * P1 + t];
    }
    if (t < IL * 3 * P2) {
        float pr = inv_binaryp[i * IL * 3 * P2 + t];
        float s = 1.0f / (1.0f + expf(-pr));
        bc_s[t] = s * inv_binary_feats[i * IL * 3 * P2 + t];
    }
    for (int idx = t; idx < BL * P1; idx += 320) {
        int o = idx >> 6, p = idx & 63;
        cuf_s[o * CUF_STRIDE + p] = 1.0f - unary_feats[b * BL * P1 + idx];
    }
    {
        const float4* src4 = reinterpret_cast<const float4*>(binary_feats + (size_t)b * BL * 24 * P2);
        float4* dst4 = reinterpret_cast<float4*>(cbf_s);
        for (int idx = t; idx < BL * 24 * P2 / 4; idx += 320) {  // 2400 float4
            int o = idx / 96, r = idx - o * 96;
            float4 x = src4[idx];
            float4 y;
            y.x = 1.0f - x.x; y.y = 1.0f - x.y; y.z = 1.0f - x.z; y.w = 1.0f - x.w;
            dst4[o * (CBF_STRIDE / 4) + r] = y;
        }
    }
    __syncthreads();

    // ---- Phase 1: t1[v][o] = prod_p (1 - uc*cuf) ----
    if (t < IL * BL) {
        int v = t / BL, o = t - v * BL;
        const float* ucv = uc_s + v * 65;
        const float* cufo = cuf_s + o * CUF_STRIDE;
        float a0 = 1.f, a1 = 1.f, a2 = 1.f, a3 = 1.f;
#pragma unroll
        for (int p = 0; p < P1; p += 4) {
            a0 *= fmaf(-ucv[p],     cufo[p],     1.f);
            a1 *= fmaf(-ucv[p + 1], cufo[p + 1], 1.f);
            a2 *= fmaf(-ucv[p + 2], cufo[p + 2], 1.f);
            a3 *= fmaf(-ucv[p + 3], cufo[p + 3], 1.f);
        }
        t1_s[t] = (a0 * a1) * (a2 * a3);
    }
    __syncthreads();

    // ---- Phase 2: per (o, v, vp) compute prod_op (1 - t1[w][oo] * t2) ----
    if (t < BL * 12) {
        int o = t / 12;
        int j = t - o * 12;        // j = v*3 + vp
        int v = j / 3;
        int vp = j - v * 3;
        int w = vp + (vp >= v ? 1 : 0);   // vothers[v][vp]

        const float4* bc4 = reinterpret_cast<const float4*>(bc_s + j * P2);
        float4 q0 = bc4[0], q1 = bc4[1], q2 = bc4[2], q3 = bc4[3];

        const float* t1w = t1_s + w * BL;
        const float* co = cbf_s + o * CBF_STRIDE;

        float prodP = 1.0f;
#pragma unroll
        for (int op = 0; op < 24; ++op) {
            int oo = op + (op >= o ? 1 : 0);   // oothers[o][op]
            float tg = t1w[oo];
            const float4* c4 = reinterpret_cast<const float4*>(co + op * P2);
            float4 c0 = c4[0], c1 = c4[1], c2 = c4[2], c3 = c4[3];
            float p0 = fmaf(-q0.x, c0.x, 1.f) * fmaf(-q0.y, c0.y, 1.f);
            float p1 = fmaf(-q0.z, c0.z, 1.f) * fmaf(-q0.w, c0.w, 1.f);
            float p2 = fmaf(-q1.x, c1.x, 1.f) * fmaf(-q1.y, c1.y, 1.f);
            float p3 = fmaf(-q1.z, c1.z, 1.f) * fmaf(-q1.w, c1.w, 1.f);
            float p4 = fmaf(-q2.x, c2.x, 1.f) * fmaf(-q2.y, c2.y, 1.f);
            float p5 = fmaf(-q2.z, c2.z, 1.f) * fmaf(-q2.w, c2.w, 1.f);
            float p6 = fmaf(-q3.x, c3.x, 1.f) * fmaf(-q3.y, c3.y, 1.f);
            float p7 = fmaf(-q3.z, c3.z, 1.f) * fmaf(-q3.w, c3.w, 1.f);
            float t2 = ((p0 * p1) * (p2 * p3)) * ((p4 * p5) * (p6 * p7));
            prodP *= fmaf(-tg, t2, 1.0f);
        }
        P_s[t] = prodP;
    }
    __syncthreads();

    // ---- Phase 3: uni = t1 * prod_vp (1 - P) ; write uni_sets ----
    if (t < IL * BL) {
        int v = t / BL, o = t - v * BL;
        int base = o * 12 + v * 3;
        float bsat = (1.0f - P_s[base]) * (1.0f - P_s[base + 1]) * (1.0f - P_s[base + 2]);
        float u = t1_s[t] * bsat;
        uni_s[t] = u;
        out[(size_t)bid * (IL * BL) + t] = u;
    }
    __syncthreads();

    // ---- Phase 4: inv_uni[b,i] = prod_v (1 - prod_o (1 - uni)) ----
    if (t < IL) {
        const float* uv = uni_s + t * BL;
        float pv = 1.0f;
#pragma unroll
        for (int o = 0; o < BL; ++o) pv *= (1.0f - uv[o]);
        ps_s[t] = 1.0f - pv;
    }
    __syncthreads();

    // ---- Phase 5: publish inv_uni; leader block (i==7) does the softmax ----
    if (t == 0) {
        float myval = (ps_s[0] * ps_s[1]) * (ps_s[2] * ps_s[3]);
        // value in [0,1] => bit pattern has sign bit 0, never equals SENTINEL
        __hip_atomic_store(&vals_ws[bid], __float_as_uint(myval),
                           __ATOMIC_RELEASE, __HIP_MEMORY_SCOPE_AGENT);
        if (i == 7) {
            float x[NI];
#pragma unroll
            for (int k = 0; k < NI; ++k) {
                unsigned int u;
                do {
                    u = __hip_atomic_load(&vals_ws[b * NI + k],
                                          __ATOMIC_RELAXED, __HIP_MEMORY_SCOPE_AGENT);
                } while (u == SENTINEL);
                x[k] = __uint_as_float(u);
            }
            const float S = logf(0.999f * 7.0f / (1.0f - 0.999f));
            float m = x[0];
#pragma unroll
            for (int k = 1; k < NI; ++k) m = fmaxf(m, x[k]);
            float s = 0.0f;
#pragma unroll
            for (int k = 0; k < NI; ++k) {
                x[k] = expf((x[k] - m) * S);
                s += x[k];
            }
            float inv = 1.0f / s;
            float* sel = out + (size_t)NB * NI * IL * BL + b * NI;
#pragma unroll
            for (int k = 0; k < NI; ++k) sel[k] = x[k] * inv;
        }
    }
}

extern "C" void kernel_launch(void* const* d_in, const int* in_sizes, int n_in,
                              void* d_out, int out_size, void* d_ws, size_t ws_size,
                              hipStream_t stream) {
    const float* inv_unary_feats  = (const float*)d_in[0];
    const float* inv_binary_feats = (const float*)d_in[1];
    const float* unary_feats      = (const float*)d_in[2];
    const float* binary_feats     = (const float*)d_in[3];
    const float* inv_unaryp       = (const float*)d_in[4];
    const float* inv_binaryp      = (const float*)d_in[5];

    float* out = (float*)d_out;                  // [0,51200) uni_sets, [51200,51712) inv_select
    unsigned int* vals_ws = (unsigned int*)d_ws; // 512 words scratch

    init_ws_kernel<<<1, NB * NI, 0, stream>>>(vals_ws);

    unify_fused_kernel<<<NB * NI, 320, 0, stream>>>(
        inv_unary_feats, inv_binary_feats, unary_feats, binary_feats,
        inv_unaryp, inv_binaryp, out, vals_ws);
}

// Round 5
// 84.652 us; speedup vs baseline: 1.0708x; 1.0708x over previous
//
#include <hip/hip_runtime.h>
#include <math.h>

// Problem constants (match reference)
#define NI 8    // invariants
#define IL 4    // vars per invariant
#define BL 25   // objects per example
#define P1 64   // unary predicates
#define P2 16   // binary predicates
#define NB 64   // batch

// LDS row strides chosen for bank-conflict avoidance / alignment:
//  cuf: [25][65]  (stride 65 -> distinct-o lanes hit distinct banks)
//  cbf: [25][392] (24*16=384 payload + 8 pad; 392%32=8 -> <=2-way on b128; 1568B rows keep 16B align)
#define CUF_STRIDE 65
#define CBF_STRIDE 392

__global__ __launch_bounds__(320) void unify_kernel(
    const float* __restrict__ inv_unary_feats,   // (8,4,64)
    const float* __restrict__ inv_binary_feats,  // (8,4,3,16)
    const float* __restrict__ unary_feats,       // (64,25,64)
    const float* __restrict__ binary_feats,      // (64,25,24,16)
    const float* __restrict__ inv_unaryp,        // (8,4,64)
    const float* __restrict__ inv_binaryp,       // (8,4,3,16)
    float* __restrict__ out_uni,                 // (64,8,4,25) flat
    float* __restrict__ inv_uni_ws)              // (64,8)
{
    __shared__ float cuf_s[BL * CUF_STRIDE];   // 1 - unary_feats[b]
    __shared__ float cbf_s[BL * CBF_STRIDE];   // 1 - binary_feats[b], padded rows
    __shared__ float uc_s[IL * 65];            // sigmoid(unaryp)*unary_feats for this i
    __shared__ float bc_s[IL * 3 * P2];        // sigmoid(binaryp)*binary_feats for this i
    __shared__ float t1_s[IL * BL];
    __shared__ float P_s[BL * 12];             // prod_op(1 - tg*t2) per (o, v*3+vp)
    __shared__ float uni_s[IL * BL];
    __shared__ float ps_s[IL];

    const int bid = blockIdx.x;
    const int b = bid >> 3;   // batch index
    const int i = bid & 7;    // invariant index
    const int t = threadIdx.x;

    // ---- Phase 0: staging ----
    // unary conds for this invariant: sigmoid(p) * feats
    if (t < IL * P1) {
        int v = t >> 6, p = t & 63;
        float pr = inv_unaryp[i * IL * P1 + t];
        float s = 1.0f / (1.0f + expf(-pr));
        uc_s[v * 65 + p] = s * inv_unary_feats[i * IL * P1 + t];
    }
    // binary conds for this invariant
    if (t < IL * 3 * P2) {
        float pr = inv_binaryp[i * IL * 3 * P2 + t];
        float s = 1.0f / (1.0f + expf(-pr));
        bc_s[t] = s * inv_binary_feats[i * IL * 3 * P2 + t];
    }
    // 1 - unary_feats[b] (padded stride 65)
    for (int idx = t; idx < BL * P1; idx += 320) {
        int o = idx >> 6, p = idx & 63;
        cuf_s[o * CUF_STRIDE + p] = 1.0f - unary_feats[b * BL * P1 + idx];
    }
    // 1 - binary_feats[b] via float4 (rows 384 payload -> padded 392)
    {
        const float4* src4 = reinterpret_cast<const float4*>(binary_feats + (size_t)b * BL * 24 * P2);
        float4* dst4 = reinterpret_cast<float4*>(cbf_s);
        for (int idx = t; idx < BL * 24 * P2 / 4; idx += 320) {  // 2400 float4
            int o = idx / 96, r = idx - o * 96;
            float4 x = src4[idx];
            float4 y;
            y.x = 1.0f - x.x; y.y = 1.0f - x.y; y.z = 1.0f - x.z; y.w = 1.0f - x.w;
            dst4[o * (CBF_STRIDE / 4) + r] = y;
        }
    }
    __syncthreads();

    // ---- Phase 1: t1[v][o] = prod_p (1 - uc*cuf) ----
    if (t < IL * BL) {
        int v = t / BL, o = t - v * BL;
        const float* ucv = uc_s + v * 65;
        const float* cufo = cuf_s + o * CUF_STRIDE;
        float a0 = 1.f, a1 = 1.f, a2 = 1.f, a3 = 1.f;
#pragma unroll
        for (int p = 0; p < P1; p += 4) {
            a0 *= fmaf(-ucv[p],     cufo[p],     1.f);
            a1 *= fmaf(-ucv[p + 1], cufo[p + 1], 1.f);
            a2 *= fmaf(-ucv[p + 2], cufo[p + 2], 1.f);
            a3 *= fmaf(-ucv[p + 3], cufo[p + 3], 1.f);
        }
        t1_s[t] = (a0 * a1) * (a2 * a3);
    }
    __syncthreads();

    // ---- Phase 2: per (o, v, vp) compute prod_op (1 - t1[w][oo] * t2) ----
    if (t < BL * 12) {
        int o = t / 12;
        int j = t - o * 12;        // j = v*3 + vp
        int v = j / 3;
        int vp = j - v * 3;
        int w = vp + (vp >= v ? 1 : 0);   // vothers[v][vp]

        const float4* bc4 = reinterpret_cast<const float4*>(bc_s + j * P2);
        float4 q0 = bc4[0], q1 = bc4[1], q2 = bc4[2], q3 = bc4[3];

        const float* t1w = t1_s + w * BL;
        const float* co = cbf_s + o * CBF_STRIDE;

        float prodP = 1.0f;
#pragma unroll
        for (int op = 0; op < 24; ++op) {
            int oo = op + (op >= o ? 1 : 0);   // oothers[o][op]
            float tg = t1w[oo];
            const float4* c4 = reinterpret_cast<const float4*>(co + op * P2);
            float4 c0 = c4[0], c1 = c4[1], c2 = c4[2], c3 = c4[3];
            float p0 = fmaf(-q0.x, c0.x, 1.f) * fmaf(-q0.y, c0.y, 1.f);
            float p1 = fmaf(-q0.z, c0.z, 1.f) * fmaf(-q0.w, c0.w, 1.f);
            float p2 = fmaf(-q1.x, c1.x, 1.f) * fmaf(-q1.y, c1.y, 1.f);
            float p3 = fmaf(-q1.z, c1.z, 1.f) * fmaf(-q1.w, c1.w, 1.f);
            float p4 = fmaf(-q2.x, c2.x, 1.f) * fmaf(-q2.y, c2.y, 1.f);
            float p5 = fmaf(-q2.z, c2.z, 1.f) * fmaf(-q2.w, c2.w, 1.f);
            float p6 = fmaf(-q3.x, c3.x, 1.f) * fmaf(-q3.y, c3.y, 1.f);
            float p7 = fmaf(-q3.z, c3.z, 1.f) * fmaf(-q3.w, c3.w, 1.f);
            float t2 = ((p0 * p1) * (p2 * p3)) * ((p4 * p5) * (p6 * p7));
            prodP *= fmaf(-tg, t2, 1.0f);
        }
        P_s[t] = prodP;
    }
    __syncthreads();

    // ---- Phase 3: uni = t1 * prod_vp (1 - P) ; write uni_sets ----
    if (t < IL * BL) {
        int v = t / BL, o = t - v * BL;
        int base = o * 12 + v * 3;
        float bsat = (1.0f - P_s[base]) * (1.0f - P_s[base + 1]) * (1.0f - P_s[base + 2]);
        float u = t1_s[t] * bsat;
        uni_s[t] = u;
        out_uni[(size_t)bid * (IL * BL) + t] = u;
    }
    __syncthreads();

    // ---- Phase 4: inv_uni[b,i] = prod_v (1 - prod_o (1 - uni)) ----
    if (t < IL) {
        const float* uv = uni_s + t * BL;
        float pv = 1.0f;
#pragma unroll
        for (int o = 0; o < BL; ++o) pv *= (1.0f - uv[o]);
        ps_s[t] = 1.0f - pv;
    }
    __syncthreads();
    if (t == 0) {
        inv_uni_ws[bid] = (ps_s[0] * ps_s[1]) * (ps_s[2] * ps_s[3]);
    }
}

__global__ __launch_bounds__(64) void softmax_kernel(
    const float* __restrict__ inv_uni,   // (64,8)
    float* __restrict__ out)             // (64,8)
{
    int b = threadIdx.x;  // 64 threads, one per batch row
    const float S = logf(0.999f * 7.0f / (1.0f - 0.999f));
    float x[NI];
    float m = -3.0e38f;
#pragma unroll
    for (int k = 0; k < NI; ++k) {
        x[k] = inv_uni[b * NI + k];
        m = fmaxf(m, x[k]);
    }
    float s = 0.0f;
#pragma unroll
    for (int k = 0; k < NI; ++k) {
        x[k] = expf((x[k] - m) * S);
        s += x[k];
    }
    float inv = 1.0f / s;
#pragma unroll
    for (int k = 0; k < NI; ++k) out[b * NI + k] = x[k] * inv;
}

extern "C" void kernel_launch(void* const* d_in, const int* in_sizes, int n_in,
                              void* d_out, int out_size, void* d_ws, size_t ws_size,
                              hipStream_t stream) {
    const float* inv_unary_feats  = (const float*)d_in[0];
    const float* inv_binary_feats = (const float*)d_in[1];
    const float* unary_feats      = (const float*)d_in[2];
    const float* binary_feats     = (const float*)d_in[3];
    const float* inv_unaryp       = (const float*)d_in[4];
    const float* inv_binaryp      = (const float*)d_in[5];

    float* out = (float*)d_out;                 // [0,51200) uni_sets, [51200,51712) inv_select
    float* inv_uni_ws = (float*)d_ws;           // 512 floats scratch

    unify_kernel<<<NB * NI, 320, 0, stream>>>(
        inv_unary_feats, inv_binary_feats, unary_feats, binary_feats,
        inv_unaryp, inv_binaryp, out, inv_uni_ws);

    softmax_kernel<<<1, 64, 0, stream>>>(inv_uni_ws, out + (size_t)NB * NI * IL * BL);
}